// Round 4
// baseline (1799.513 us; speedup 1.0000x reference)
//
#include <hip/hip_runtime.h>
#include <hip/hip_bf16.h>

typedef __bf16 bf16x8 __attribute__((ext_vector_type(8)));
typedef float  f32x4  __attribute__((ext_vector_type(4)));
typedef short  s16x4  __attribute__((ext_vector_type(4)));
typedef unsigned short u16;

#define L2E 1.44269504088896f

static __device__ __forceinline__ u16 f2bf(float f) {
  unsigned u = __builtin_bit_cast(unsigned, f);
  u += 0x7fffu + ((u >> 16) & 1u);
  return (u16)(u >> 16);
}

static __device__ __forceinline__ void gld_lds16(const void* g, void* l) {
  __builtin_amdgcn_global_load_lds((const __attribute__((address_space(1))) unsigned*)g,
                                   (__attribute__((address_space(3))) unsigned*)l, 16, 0, 0);
}

// ---------------------------------------------------------------------------
// fp32 -> bf16 conversion (weights)
// ---------------------------------------------------------------------------
__global__ __launch_bounds__(256)
void cvtk(const float* __restrict__ s, u16* __restrict__ d, int n) {
  const int i = (blockIdx.x * 256 + threadIdx.x) * 4;
  if (i >= n) return;
  const float4 f = *(const float4*)(s + i);
  s16x4 p;
  p[0] = (short)f2bf(f.x); p[1] = (short)f2bf(f.y);
  p[2] = (short)f2bf(f.z); p[3] = (short)f2bf(f.w);
  *(s16x4*)(d + i) = p;
}

// ---------------------------------------------------------------------------
// LayerNorm: one wave per token (768 cols = 12 f32/lane).
// ---------------------------------------------------------------------------
__global__ __launch_bounds__(256)
void lnk(const float* __restrict__ x, const float* __restrict__ gw,
         const float* __restrict__ bw, u16* __restrict__ y,
         u16* __restrict__ xv, int viewmajor) {
  const int lane = threadIdx.x & 63;
  const int tok = blockIdx.x * 4 + (threadIdx.x >> 6);
  const float* xr = x + (size_t)tok * 768;
  float4 v[3];
  float s = 0.f, sq = 0.f;
#pragma unroll
  for (int j = 0; j < 3; ++j) {
    v[j] = *(const float4*)(xr + j * 256 + lane * 4);
    s  += v[j].x + v[j].y + v[j].z + v[j].w;
    sq += v[j].x * v[j].x + v[j].y * v[j].y + v[j].z * v[j].z + v[j].w * v[j].w;
  }
#pragma unroll
  for (int o = 1; o < 64; o <<= 1) { s += __shfl_xor(s, o); sq += __shfl_xor(sq, o); }
  const float mean = s * (1.f / 768.f);
  const float var  = sq * (1.f / 768.f) - mean * mean;
  const float rstd = rsqrtf(var + 1e-5f);
  size_t yrow = (size_t)tok;
  if (viewmajor) {
    const int b_ = tok >> 14, vv = (tok >> 13) & 1, l_ = tok & 8191;
    yrow = ((size_t)((vv << 2) + b_) << 13) + l_;
  }
#pragma unroll
  for (int j = 0; j < 3; ++j) {
    const float4 g4 = *(const float4*)(gw + j * 256 + lane * 4);
    const float4 b4 = *(const float4*)(bw + j * 256 + lane * 4);
    s16x4 py;
    py[0] = (short)f2bf((v[j].x - mean) * rstd * g4.x + b4.x);
    py[1] = (short)f2bf((v[j].y - mean) * rstd * g4.y + b4.y);
    py[2] = (short)f2bf((v[j].z - mean) * rstd * g4.z + b4.z);
    py[3] = (short)f2bf((v[j].w - mean) * rstd * g4.w + b4.w);
    *(s16x4*)(y + yrow * 768 + j * 256 + lane * 4) = py;
    if (xv) {
      s16x4 px;
      px[0] = (short)f2bf(v[j].x); px[1] = (short)f2bf(v[j].y);
      px[2] = (short)f2bf(v[j].z); px[3] = (short)f2bf(v[j].w);
      *(s16x4*)(xv + yrow * 768 + j * 256 + lane * 4) = px;
    }
  }
}

// ---------------------------------------------------------------------------
// GEMM C = A(MxK,bf16) * B(NxK,bf16)^T + bias, tile 128x128, BK=64,
// 4 waves (2x2 of 64x64), 16x16x32 MFMA.
// Counted-vmcnt 2-phase pipeline (T3/T4): per K-tile, phase 0 computes the
// m-lower half (acc rows 0,1) and stages {B(4) + A chunks 0,2} of tile t+1;
// phase 1 computes the m-upper half and stages {A chunks 1,3}. Waits are
// vmcnt(2)/vmcnt(6) in steady state (never 0); ONE barrier per K-tile.
// Safety: phase-p stage overwrites regions last ds_read at iter t-1 phase p,
// complete (lgkmcnt before MFMA) before iter t phase 0's barrier.
// XCD-bijective blockIdx swizzle (T1): all grids divisible by 8.
// ---------------------------------------------------------------------------
template<int MODE>
__global__ __launch_bounds__(256)
void gemm_bt(const u16* __restrict__ A, const u16* __restrict__ B,
             const float* __restrict__ bias, void* __restrict__ Cp,
             int N, int K, int Mtiles,
             const float* __restrict__ xres, const int* __restrict__ idxp,
             int vview) {
  __shared__ char lds[2][2][16384];
  const int t = threadIdx.x;
  const int lane = t & 63;
  const int wid = t >> 6;
  const int wr = wid >> 1, wc = wid & 1;

  // XCD-aware swizzle: XCD (blockIdx%8) owns a contiguous chunk of panels.
  const int cpx = gridDim.x >> 3;
  const int bid = (blockIdx.x & 7) * cpx + (blockIdx.x >> 3);

  const int Ntiles = N >> 7;
  const int PPB = Ntiles << 4;       // 16 M-tiles per panel: A-strip L2-hot
  const int panel = bid / PPB;
  const int rem = bid - panel * PPB;
  const int nt = rem >> 4;
  const int mt = (panel << 4) + (rem & 15);

  const int srow = t >> 3;                         // 0..31
  const int scol = (((t & 7) ^ (srow & 7)) << 3);  // inverse-swizzled k
  const u16* As = A + (size_t)(mt * 128 + srow) * K + scol;
  const u16* Bs = B + (size_t)(nt * 128 + srow) * K + scol;
  const int ldsoff = wid << 10;

  f32x4 acc[4][4] = {};
  const int nk = K >> 6;

  // phase-0 staging: B chunks 0..3 (rows 0..127) + A chunks 0,2 (rows 0-31,64-95)
  auto stage_p0 = [&](int buf, int kt) {
    const u16* a = As + kt * 64;
    const u16* b = Bs + kt * 64;
#pragma unroll
    for (int c = 0; c < 4; ++c)
      gld_lds16(b + (size_t)c * 32 * K, lds[buf][1] + (c << 12) + ldsoff);
    gld_lds16(a,                     lds[buf][0] + (0 << 12) + ldsoff);
    gld_lds16(a + (size_t)2 * 32 * K, lds[buf][0] + (2 << 12) + ldsoff);
  };
  // phase-1 staging: A chunks 1,3 (rows 32-63, 96-127)
  auto stage_p1 = [&](int buf, int kt) {
    const u16* a = As + kt * 64;
    gld_lds16(a + (size_t)1 * 32 * K, lds[buf][0] + (1 << 12) + ldsoff);
    gld_lds16(a + (size_t)3 * 32 * K, lds[buf][0] + (3 << 12) + ldsoff);
  };

  stage_p0(0, 0);
  stage_p1(0, 0);

  for (int kt = 0; kt < nk; ++kt) {
    const int cur = kt & 1;
    const char* La = lds[cur][0];
    const char* Lb = lds[cur][1];
    const bool pre = (kt + 1 < nk);

    // ---- phase 0: needs tile-t p0 group (oldest 6); t's p1 (2) may fly ----
    asm volatile("s_waitcnt vmcnt(2)" ::: "memory");
    __syncthreads();
    if (pre) stage_p0(cur ^ 1, kt + 1);

    bf16x8 bfv[2][4], af[2][2];
#pragma unroll
    for (int ks = 0; ks < 2; ++ks) {
      const int cby = (ks << 6) + ((lane >> 4) << 4);
#pragma unroll
      for (int i = 0; i < 2; ++i) {
        const int ra = wr * 64 + i * 16 + (lane & 15);
        af[ks][i] = *(const bf16x8*)(La + ra * 128 + (cby ^ ((ra & 7) << 4)));
      }
#pragma unroll
      for (int j = 0; j < 4; ++j) {
        const int rb = wc * 64 + j * 16 + (lane & 15);
        bfv[ks][j] = *(const bf16x8*)(Lb + rb * 128 + (cby ^ ((rb & 7) << 4)));
      }
    }
#pragma unroll
    for (int ks = 0; ks < 2; ++ks)
#pragma unroll
      for (int i = 0; i < 2; ++i)
#pragma unroll
        for (int j = 0; j < 4; ++j)
          acc[i][j] = __builtin_amdgcn_mfma_f32_16x16x32_bf16(af[ks][i], bfv[ks][j], acc[i][j], 0, 0, 0);

    // ---- phase 1: needs tile-t p1 group; t+1's p0 (6) may fly ----
    if (pre) asm volatile("s_waitcnt vmcnt(6)" ::: "memory");
    else     asm volatile("s_waitcnt vmcnt(0)" ::: "memory");
    if (pre) stage_p1(cur ^ 1, kt + 1);

    bf16x8 af2[2][2];
#pragma unroll
    for (int ks = 0; ks < 2; ++ks) {
      const int cby = (ks << 6) + ((lane >> 4) << 4);
#pragma unroll
      for (int i = 0; i < 2; ++i) {
        const int ra = wr * 64 + (i + 2) * 16 + (lane & 15);
        af2[ks][i] = *(const bf16x8*)(La + ra * 128 + (cby ^ ((ra & 7) << 4)));
      }
    }
#pragma unroll
    for (int ks = 0; ks < 2; ++ks)
#pragma unroll
      for (int i = 0; i < 2; ++i)
#pragma unroll
        for (int j = 0; j < 4; ++j)
          acc[i + 2][j] = __builtin_amdgcn_mfma_f32_16x16x32_bf16(af2[ks][i], bfv[ks][j], acc[i + 2][j], 0, 0, 0);
  }

  int shift = 0;
  if constexpr (MODE == 2) shift = (idxp[0] & 1) ? 256 : 0;

  const int rb0 = mt * 128 + wr * 64 + ((lane >> 4) << 2);
  const int cb0 = nt * 128 + wc * 64 + (lane & 15);
#pragma unroll
  for (int i = 0; i < 4; ++i) {
    const int row = rb0 + i * 16;
#pragma unroll
    for (int j = 0; j < 4; ++j) {
      const int col = cb0 + j * 16;
      const float bv = bias[col];
      if constexpr (MODE == 0) {
        u16* C = (u16*)Cp;
#pragma unroll
        for (int r = 0; r < 4; ++r)
          C[(size_t)(row + r) * N + col] = f2bf(acc[i][j][r] + bv);
      } else if constexpr (MODE == 1) {
        u16* C = (u16*)Cp;
        const int hh = col >> 6, dd = col & 63;
        const int b_ = row >> 13, l_ = row & 8191;
        s16x4 pk;
#pragma unroll
        for (int r = 0; r < 4; ++r) pk[r] = (short)f2bf(acc[i][j][r] + bv);
        *(s16x4*)(C + (((size_t)((b_ * 12 + hh) << 6) + dd) << 13) + l_) = pk;
      } else if constexpr (MODE == 2) {
        float* C = (float*)Cp;
        const int b_ = row >> 13, p_ = row & 8191;
        const int l0 = (p_ - shift) & 8191;
        const size_t rbase = ((size_t)((b_ << 1) + vview) << 13) + l0;
#pragma unroll
        for (int r = 0; r < 4; ++r) {
          const size_t idx = (rbase + r) * 768 + col;
          C[idx] = xres[idx] + acc[i][j][r] + bv;
        }
      } else if constexpr (MODE == 3) {
        u16* C = (u16*)Cp;
#pragma unroll
        for (int r = 0; r < 4; ++r) {
          const float u = acc[i][j][r] + bv;
          const float e = __builtin_amdgcn_exp2f(-2.45546693f * u);
          C[(size_t)(row + r) * N + col] = f2bf(u / (1.f + e));
        }
      } else {
        float* C = (float*)Cp;
#pragma unroll
        for (int r = 0; r < 4; ++r) {
          const size_t idx = (size_t)(row + r) * 768 + col;
          C[idx] = C[idx] + acc[i][j][r] + bv;
        }
      }
    }
  }
}

// ---------------------------------------------------------------------------
// Windowed cross-view attention, no-max softmax (scores bounded; softmax is
// shift-invariant). One wave = 64 queries (4 q-tiles) of one (att,b,win,head).
// Swapped QK^T (mfma(K,Q) -> S^T) makes P lane-local; PV mfma_16x16x16bf16_1k
// B-layout equals the S^T C-layout (zero shuffles).
// ---------------------------------------------------------------------------
__global__ __launch_bounds__(256)
void attnk(const u16* __restrict__ Q1, const u16* __restrict__ K1, const u16* __restrict__ V1,
           const u16* __restrict__ Q2, const u16* __restrict__ K2, const u16* __restrict__ V2,
           u16* __restrict__ O, const int* __restrict__ idxp) {
  const int lane = threadIdx.x & 63;
  const int c = lane & 15, g = lane >> 4;
  const int unit = blockIdx.x * 4 + (threadIdx.x >> 6);
  const int qc = unit & 7;
  int u2 = unit >> 3;
  const int h = u2 % 12; u2 /= 12;
  const int w = u2 & 15; u2 >>= 4;
  const int b = u2 & 3;
  const int a = u2 >> 2;
  const int shift = (idxp[0] & 1) ? 256 : 0;

  const u16* Q  = a ? Q2 : Q1;
  const u16* Kb = a ? K2 : K1;
  const u16* Vt = a ? V2 : V1;

  const int qrow0 = b * 8192 + w * 512 + qc * 64;
  bf16x8 qf[4][2];
#pragma unroll
  for (int q = 0; q < 4; ++q)
#pragma unroll
    for (int hf = 0; hf < 2; ++hf)
      qf[q][hf] = *(const bf16x8*)(Q + (size_t)(qrow0 + q * 16 + c) * 768 + h * 64 + hf * 32 + g * 8);

  f32x4 oacc[4][4] = {};   // [df][q]
  f32x4 psum[4] = {};      // [q] per-lane partial softmax denominators
  const short* Vts = (const short*)Vt + (((size_t)((b * 12 + h) << 6)) << 13);
  const int kbase = b * 8192 + w * 512;
  const float CEXP = 0.125f * L2E;  // fold 1/sqrt(64) into exp2 argument

  for (int kt = 0; kt < 32; ++kt) {
    const size_t krow = (size_t)(kbase + kt * 16 + c) * 768 + h * 64 + g * 8;
    const bf16x8 kf0 = *(const bf16x8*)(Kb + krow);
    const bf16x8 kf1 = *(const bf16x8*)(Kb + krow + 32);
    const int lv = (w * 512 + kt * 16 + g * 4 - shift) & 8191;
    s16x4 vf[4];
#pragma unroll
    for (int df = 0; df < 4; ++df)
      vf[df] = *(const s16x4*)(Vts + ((size_t)(df * 16 + c) << 13) + lv);

    const f32x4 z = {0.f, 0.f, 0.f, 0.f};
    s16x4 pk[4];
#pragma unroll
    for (int q = 0; q < 4; ++q) {
      f32x4 sc = __builtin_amdgcn_mfma_f32_16x16x32_bf16(kf0, qf[q][0], z, 0, 0, 0);
      sc = __builtin_amdgcn_mfma_f32_16x16x32_bf16(kf1, qf[q][1], sc, 0, 0, 0);
      f32x4 pv;
      pv[0] = __builtin_amdgcn_exp2f(sc[0] * CEXP);
      pv[1] = __builtin_amdgcn_exp2f(sc[1] * CEXP);
      pv[2] = __builtin_amdgcn_exp2f(sc[2] * CEXP);
      pv[3] = __builtin_amdgcn_exp2f(sc[3] * CEXP);
      psum[q] += pv;
      pk[q][0] = (short)f2bf(pv[0]);
      pk[q][1] = (short)f2bf(pv[1]);
      pk[q][2] = (short)f2bf(pv[2]);
      pk[q][3] = (short)f2bf(pv[3]);
    }
#pragma unroll
    for (int df = 0; df < 4; ++df)
#pragma unroll
      for (int q = 0; q < 4; ++q)
        oacc[df][q] = __builtin_amdgcn_mfma_f32_16x16x16bf16_1k(vf[df], pk[q], oacc[df][q], 0, 0, 0);
  }

  const size_t orow0 = (size_t)(a * 32768 + qrow0);
#pragma unroll
  for (int q = 0; q < 4; ++q) {
    float ss = psum[q][0] + psum[q][1] + psum[q][2] + psum[q][3];
    ss += __shfl_xor(ss, 16);
    ss += __shfl_xor(ss, 32);
    const float inv = 1.f / ss;
#pragma unroll
    for (int df = 0; df < 4; ++df) {
      s16x4 po;
#pragma unroll
      for (int r = 0; r < 4; ++r) po[r] = (short)f2bf(oacc[df][q][r] * inv);
      *(s16x4*)(O + (orow0 + q * 16 + c) * 768 + h * 64 + df * 16 + g * 4) = po;
    }
  }
}

// ---------------------------------------------------------------------------
extern "C" void kernel_launch(void* const* d_in, const int* in_sizes, int n_in,
                              void* d_out, int out_size, void* d_ws, size_t ws_size,
                              hipStream_t stream) {
  const float* x       = (const float*)d_in[0];
  const float* ln1_g   = (const float*)d_in[1];
  const float* ln1_b   = (const float*)d_in[2];
  const float* ln2_g   = (const float*)d_in[3];
  const float* ln2_b   = (const float*)d_in[4];
  const float* a1_wqkv = (const float*)d_in[5];
  const float* a1_bqkv = (const float*)d_in[6];
  const float* a1_wo   = (const float*)d_in[7];
  const float* a1_bo   = (const float*)d_in[8];
  const float* a2_wqkv = (const float*)d_in[9];
  const float* a2_bqkv = (const float*)d_in[10];
  const float* a2_wo   = (const float*)d_in[11];
  const float* a2_bo   = (const float*)d_in[12];
  const float* fc_w    = (const float*)d_in[13];
  const float* fc_b    = (const float*)d_in[14];
  const float* proj_w  = (const float*)d_in[15];
  const float* proj_b  = (const float*)d_in[16];
  const int*   idxp    = (const int*)d_in[17];
  float* out = (float*)d_out;

  u16* p = (u16*)d_ws;
  u16* w1  = p; p += (size_t)2304 * 768;
  u16* w2  = p; p += (size_t)2304 * 768;
  u16* wo1 = p; p += (size_t)768 * 768;
  u16* wo2 = p; p += (size_t)768 * 768;
  u16* fcw = p; p += (size_t)3072 * 768;
  u16* pjw = p; p += (size_t)768 * 3072;
  u16* y   = p; p += (size_t)65536 * 768;
  u16* xv  = p; p += (size_t)65536 * 768;
  u16* Q1  = p; p += (size_t)32768 * 768;
  u16* K1  = p; p += (size_t)32768 * 768;
  u16* V1  = p; p += (size_t)32768 * 768;
  u16* Q2  = p; p += (size_t)32768 * 768;
  u16* K2  = p; p += (size_t)32768 * 768;
  u16* V2  = p; p += (size_t)32768 * 768;
  u16* Ob  = p; p += (size_t)65536 * 768;
  u16* hb  = Q1;  // MLP hidden aliases Q1..Ob

  cvtk<<<1728, 256, 0, stream>>>(a1_wqkv, w1, 2304 * 768);
  cvtk<<<1728, 256, 0, stream>>>(a2_wqkv, w2, 2304 * 768);
  cvtk<<<576,  256, 0, stream>>>(a1_wo, wo1, 768 * 768);
  cvtk<<<576,  256, 0, stream>>>(a2_wo, wo2, 768 * 768);
  cvtk<<<2304, 256, 0, stream>>>(fc_w, fcw, 3072 * 768);
  cvtk<<<2304, 256, 0, stream>>>(proj_w, pjw, 768 * 3072);

  lnk<<<16384, 256, 0, stream>>>(x, ln1_g, ln1_b, y, xv, 1);

  const size_t VS = (size_t)32768 * 768;
  gemm_bt<0><<<1536, 256, 0, stream>>>(y,        w1,                  a1_bqkv,        Q1, 768, 768, 256, nullptr, nullptr, 0);
  gemm_bt<0><<<1536, 256, 0, stream>>>(y + VS,   w1 + 768 * 768,      a1_bqkv + 768,  K1, 768, 768, 256, nullptr, nullptr, 0);
  gemm_bt<1><<<1536, 256, 0, stream>>>(xv,       w1 + 2 * 768 * 768,  a1_bqkv + 1536, V1, 768, 768, 256, nullptr, nullptr, 0);
  gemm_bt<0><<<1536, 256, 0, stream>>>(y + VS,   w2,                  a2_bqkv,        Q2, 768, 768, 256, nullptr, nullptr, 0);
  gemm_bt<0><<<1536, 256, 0, stream>>>(y,        w2 + 768 * 768,      a2_bqkv + 768,  K2, 768, 768, 256, nullptr, nullptr, 0);
  gemm_bt<1><<<1536, 256, 0, stream>>>(xv + VS,  w2 + 2 * 768 * 768,  a2_bqkv + 1536, V2, 768, 768, 256, nullptr, nullptr, 0);

  attnk<<<3072, 256, 0, stream>>>(Q1, K1, V1, Q2, K2, V2, Ob, idxp);

  gemm_bt<2><<<1536, 256, 0, stream>>>(Ob,      wo1, a1_bo, out, 768, 768, 256, x, idxp, 0);
  gemm_bt<2><<<1536, 256, 0, stream>>>(Ob + VS, wo2, a2_bo, out, 768, 768, 256, x, idxp, 1);

  lnk<<<16384, 256, 0, stream>>>(out, ln2_g, ln2_b, y, nullptr, 0);

  gemm_bt<3><<<12288, 256, 0, stream>>>(y, fcw, fc_b, hb, 3072, 768, 512, nullptr, nullptr, 0);

  gemm_bt<4><<<3072, 256, 0, stream>>>(hb, pjw, proj_b, out, 768, 3072, 512, nullptr, nullptr, 0);
}

// Round 5
// 1665.948 us; speedup vs baseline: 1.0802x; 1.0802x over previous
//
#include <hip/hip_runtime.h>
#include <hip/hip_bf16.h>

typedef __bf16 bf16x8 __attribute__((ext_vector_type(8)));
typedef float  f32x4  __attribute__((ext_vector_type(4)));
typedef short  s16x4  __attribute__((ext_vector_type(4)));
typedef unsigned short u16;

#define L2E 1.44269504088896f

static __device__ __forceinline__ u16 f2bf(float f) {
  unsigned u = __builtin_bit_cast(unsigned, f);
  u += 0x7fffu + ((u >> 16) & 1u);
  return (u16)(u >> 16);
}

static __device__ __forceinline__ void gld_lds16(const void* g, void* l) {
  __builtin_amdgcn_global_load_lds((const __attribute__((address_space(1))) unsigned*)g,
                                   (__attribute__((address_space(3))) unsigned*)l, 16, 0, 0);
}

// ---------------------------------------------------------------------------
// fp32 -> bf16 conversion (weights)
// ---------------------------------------------------------------------------
__global__ __launch_bounds__(256)
void cvtk(const float* __restrict__ s, u16* __restrict__ d, int n) {
  const int i = (blockIdx.x * 256 + threadIdx.x) * 4;
  if (i >= n) return;
  const float4 f = *(const float4*)(s + i);
  s16x4 p;
  p[0] = (short)f2bf(f.x); p[1] = (short)f2bf(f.y);
  p[2] = (short)f2bf(f.z); p[3] = (short)f2bf(f.w);
  *(s16x4*)(d + i) = p;
}

// ---------------------------------------------------------------------------
// LayerNorm: one wave per token (768 cols = 12 f32/lane).
// ---------------------------------------------------------------------------
__global__ __launch_bounds__(256)
void lnk(const float* __restrict__ x, const float* __restrict__ gw,
         const float* __restrict__ bw, u16* __restrict__ y,
         u16* __restrict__ xv, int viewmajor) {
  const int lane = threadIdx.x & 63;
  const int tok = blockIdx.x * 4 + (threadIdx.x >> 6);
  const float* xr = x + (size_t)tok * 768;
  float4 v[3];
  float s = 0.f, sq = 0.f;
#pragma unroll
  for (int j = 0; j < 3; ++j) {
    v[j] = *(const float4*)(xr + j * 256 + lane * 4);
    s  += v[j].x + v[j].y + v[j].z + v[j].w;
    sq += v[j].x * v[j].x + v[j].y * v[j].y + v[j].z * v[j].z + v[j].w * v[j].w;
  }
#pragma unroll
  for (int o = 1; o < 64; o <<= 1) { s += __shfl_xor(s, o); sq += __shfl_xor(sq, o); }
  const float mean = s * (1.f / 768.f);
  const float var  = sq * (1.f / 768.f) - mean * mean;
  const float rstd = rsqrtf(var + 1e-5f);
  size_t yrow = (size_t)tok;
  if (viewmajor) {
    const int b_ = tok >> 14, vv = (tok >> 13) & 1, l_ = tok & 8191;
    yrow = ((size_t)((vv << 2) + b_) << 13) + l_;
  }
#pragma unroll
  for (int j = 0; j < 3; ++j) {
    const float4 g4 = *(const float4*)(gw + j * 256 + lane * 4);
    const float4 b4 = *(const float4*)(bw + j * 256 + lane * 4);
    s16x4 py;
    py[0] = (short)f2bf((v[j].x - mean) * rstd * g4.x + b4.x);
    py[1] = (short)f2bf((v[j].y - mean) * rstd * g4.y + b4.y);
    py[2] = (short)f2bf((v[j].z - mean) * rstd * g4.z + b4.z);
    py[3] = (short)f2bf((v[j].w - mean) * rstd * g4.w + b4.w);
    *(s16x4*)(y + yrow * 768 + j * 256 + lane * 4) = py;
    if (xv) {
      s16x4 px;
      px[0] = (short)f2bf(v[j].x); px[1] = (short)f2bf(v[j].y);
      px[2] = (short)f2bf(v[j].z); px[3] = (short)f2bf(v[j].w);
      *(s16x4*)(xv + yrow * 768 + j * 256 + lane * 4) = px;
    }
  }
}

// ---------------------------------------------------------------------------
// GEMM C = A(MxK,bf16) * B(NxK,bf16)^T + bias. Tile 256x256, BK=64, 8 waves
// (2M x 4N), per-wave 128x64 output, 16x16x32 MFMA, XOR-swizzled LDS
// (inverse-swizzle on global source of global_load_lds).
// Pipeline: 2 K-tile LDS slots; group kt: issue stage of kt+1 into slot d^1
// (free since kt-1's readers passed the last barrier), compute 4 quadrants
// from slot d, then vmcnt(0) (issued a full group earlier -> retires ~free)
// + raw s_barrier (no implicit drain; ds_reads all consumed by MFMAs before
// the barrier). ONE barrier per K-tile.
// ---------------------------------------------------------------------------
template<int MODE>
__global__ __launch_bounds__(512, 2)
void gemm_bt(const u16* __restrict__ A, const u16* __restrict__ B,
             const float* __restrict__ bias, void* __restrict__ Cp,
             int N, int K,
             const float* __restrict__ xres, const int* __restrict__ idxp,
             int vview) {
  __shared__ char lds[131072];          // A: [2slot][2half][128][128B] @0; B same @65536
  const int t = threadIdx.x;
  const int lane = t & 63;
  const int wid = t >> 6;               // 0..7
  const int wm = wid >> 2, wn = wid & 3;

  // XCD-bijective swizzle (grid % 8 == 0 for all launches)
  const int cpx = gridDim.x >> 3;
  const int bid = (blockIdx.x & 7) * cpx + (blockIdx.x >> 3);

  const int Ntiles = N >> 8;
  const int PPB = Ntiles << 3;          // 8 M-tiles per panel
  const int panel = bid / PPB;
  const int rem = bid - panel * PPB;
  const int nt = rem >> 3;
  const int mt = (panel << 3) + (rem & 7);

  // staging source (per thread): row t>>3, 16B-chunk t&7, inverse-swizzled k
  const int ra = t >> 3;
  const int sc = ((t & 7) ^ (ra & 7)) << 3;
  const u16* Asrc = A + (size_t)(mt * 256 + ra) * K + sc;
  const u16* Bsrc = B + (size_t)(nt * 256 + ra) * K + sc;
  char* LA = (char*)lds;
  char* LB = (char*)lds + 65536;
  const int wdst = wid << 10;           // wave-uniform dest base (HW adds lane*16)

  auto stageA = [&](int d, int kt) {
#pragma unroll
    for (int h = 0; h < 2; ++h) {
      const u16* s = Asrc + (size_t)kt * 64 + (size_t)(h * 128) * K;
      char* dst = LA + (d * 2 + h) * 16384 + wdst;
      gld_lds16(s, dst);
      gld_lds16(s + (size_t)64 * K, dst + 8192);
    }
  };
  auto stageB = [&](int d, int kt) {
#pragma unroll
    for (int h = 0; h < 2; ++h) {
      const u16* s = Bsrc + (size_t)kt * 64 + (size_t)(h * 128) * K;
      char* dst = LB + (d * 2 + h) * 16384 + wdst;
      gld_lds16(s, dst);
      gld_lds16(s + (size_t)64 * K, dst + 8192);
    }
  };

  // per-thread read constants
  const int c15 = lane & 15;
  const int swz = (lane & 7) << 4;
  const int cb0 = (((lane >> 4) << 4)) ^ swz;       // ks=0 col bytes
  const int cb1 = (64 | ((lane >> 4) << 4)) ^ swz;  // ks=1 col bytes
  const int bofs = (wn & 1) * 64;

  f32x4 acc[8][4] = {};
  const int nk = K >> 6;

  // prologue: kt0 -> slot 0
  stageA(0, 0); stageB(0, 0);
  asm volatile("s_waitcnt vmcnt(0)" ::: "memory");
  __builtin_amdgcn_s_barrier();
  __builtin_amdgcn_sched_barrier(0);

  for (int kt = 0; kt < nk; ++kt) {
    const int d = kt & 1;
    if (kt + 1 < nk) { stageA(d ^ 1, kt + 1); stageB(d ^ 1, kt + 1); }
    __builtin_amdgcn_sched_barrier(0);

    const char* lA = LA + (d * 2 + wm) * 16384;
    const char* lB = LB + (d * 2 + (wn >> 1)) * 16384;

    auto rdA = [&](bf16x8 (&av)[4][2], int mh) {
#pragma unroll
      for (int m = 0; m < 4; ++m) {
        const char* r = lA + (mh * 64 + m * 16 + c15) * 128;
        av[m][0] = *(const bf16x8*)(r + cb0);
        av[m][1] = *(const bf16x8*)(r + cb1);
      }
    };
    auto rdB = [&](bf16x8 (&bv)[2][2], int nh) {
#pragma unroll
      for (int n = 0; n < 2; ++n) {
        const char* r = lB + (bofs + nh * 32 + n * 16 + c15) * 128;
        bv[n][0] = *(const bf16x8*)(r + cb0);
        bv[n][1] = *(const bf16x8*)(r + cb1);
      }
    };
    auto mm = [&](bf16x8 (&av)[4][2], bf16x8 (&bv)[2][2], int mq, int nq) {
      __builtin_amdgcn_s_setprio(1);
#pragma unroll
      for (int ks = 0; ks < 2; ++ks)
#pragma unroll
        for (int m = 0; m < 4; ++m)
#pragma unroll
          for (int n = 0; n < 2; ++n)
            acc[mq * 4 + m][nq * 2 + n] = __builtin_amdgcn_mfma_f32_16x16x32_bf16(
                av[m][ks], bv[n][ks], acc[mq * 4 + m][nq * 2 + n], 0, 0, 0);
      __builtin_amdgcn_s_setprio(0);
    };

    bf16x8 av[4][2], bv[2][2];
    rdA(av, 0); rdB(bv, 0); mm(av, bv, 0, 0);
    rdB(bv, 1);             mm(av, bv, 0, 1);
    rdA(av, 1);             mm(av, bv, 1, 1);
    rdB(bv, 0);             mm(av, bv, 1, 0);

    asm volatile("s_waitcnt vmcnt(0)" ::: "memory");
    __builtin_amdgcn_s_barrier();
    __builtin_amdgcn_sched_barrier(0);
  }

  int shift = 0;
  if constexpr (MODE == 2) shift = (idxp[0] & 1) ? 256 : 0;

  const int rb0 = mt * 256 + wm * 128 + ((lane >> 4) << 2);
  const int cbase = nt * 256 + wn * 64 + c15;
#pragma unroll
  for (int mi = 0; mi < 8; ++mi) {
    const int row = rb0 + mi * 16;
#pragma unroll
    for (int nj = 0; nj < 4; ++nj) {
      const int col = cbase + nj * 16;
      const float bv = bias[col];
      if constexpr (MODE == 0) {
        u16* C = (u16*)Cp;
#pragma unroll
        for (int r = 0; r < 4; ++r)
          C[(size_t)(row + r) * N + col] = f2bf(acc[mi][nj][r] + bv);
      } else if constexpr (MODE == 1) {
        u16* C = (u16*)Cp;
        const int hh = col >> 6, dd = col & 63;
        const int b_ = row >> 13, l_ = row & 8191;
        s16x4 pk;
#pragma unroll
        for (int r = 0; r < 4; ++r) pk[r] = (short)f2bf(acc[mi][nj][r] + bv);
        *(s16x4*)(C + (((size_t)((b_ * 12 + hh) << 6) + dd) << 13) + l_) = pk;
      } else if constexpr (MODE == 2) {
        float* C = (float*)Cp;
        const int b_ = row >> 13, p_ = row & 8191;
        const int l0 = (p_ - shift) & 8191;
        const size_t rbase = ((size_t)((b_ << 1) + vview) << 13) + l0;
#pragma unroll
        for (int r = 0; r < 4; ++r) {
          const size_t idx = (rbase + r) * 768 + col;
          C[idx] = xres[idx] + acc[mi][nj][r] + bv;
        }
      } else if constexpr (MODE == 3) {
        u16* C = (u16*)Cp;
#pragma unroll
        for (int r = 0; r < 4; ++r) {
          const float u = acc[mi][nj][r] + bv;
          const float e = __builtin_amdgcn_exp2f(-2.45546693f * u);
          C[(size_t)(row + r) * N + col] = f2bf(u / (1.f + e));
        }
      } else {
        float* C = (float*)Cp;
#pragma unroll
        for (int r = 0; r < 4; ++r) {
          const size_t idx = (size_t)(row + r) * 768 + col;
          C[idx] = C[idx] + acc[mi][nj][r] + bv;
        }
      }
    }
  }
}

// ---------------------------------------------------------------------------
// Windowed cross-view attention, no-max softmax (scores bounded; softmax is
// shift-invariant). One wave = 64 queries (4 q-tiles) of one (att,b,win,head).
// Swapped QK^T (mfma(K,Q) -> S^T) makes P lane-local; PV mfma_16x16x16bf16_1k
// B-layout equals the S^T C-layout (zero shuffles).
// ---------------------------------------------------------------------------
__global__ __launch_bounds__(256)
void attnk(const u16* __restrict__ Q1, const u16* __restrict__ K1, const u16* __restrict__ V1,
           const u16* __restrict__ Q2, const u16* __restrict__ K2, const u16* __restrict__ V2,
           u16* __restrict__ O, const int* __restrict__ idxp) {
  const int lane = threadIdx.x & 63;
  const int c = lane & 15, g = lane >> 4;
  const int unit = blockIdx.x * 4 + (threadIdx.x >> 6);
  const int qc = unit & 7;
  int u2 = unit >> 3;
  const int h = u2 % 12; u2 /= 12;
  const int w = u2 & 15; u2 >>= 4;
  const int b = u2 & 3;
  const int a = u2 >> 2;
  const int shift = (idxp[0] & 1) ? 256 : 0;

  const u16* Q  = a ? Q2 : Q1;
  const u16* Kb = a ? K2 : K1;
  const u16* Vt = a ? V2 : V1;

  const int qrow0 = b * 8192 + w * 512 + qc * 64;
  bf16x8 qf[4][2];
#pragma unroll
  for (int q = 0; q < 4; ++q)
#pragma unroll
    for (int hf = 0; hf < 2; ++hf)
      qf[q][hf] = *(const bf16x8*)(Q + (size_t)(qrow0 + q * 16 + c) * 768 + h * 64 + hf * 32 + g * 8);

  f32x4 oacc[4][4] = {};   // [df][q]
  f32x4 psum[4] = {};      // [q] per-lane partial softmax denominators
  const short* Vts = (const short*)Vt + (((size_t)((b * 12 + h) << 6)) << 13);
  const int kbase = b * 8192 + w * 512;
  const float CEXP = 0.125f * L2E;

  for (int kt = 0; kt < 32; ++kt) {
    const size_t krow = (size_t)(kbase + kt * 16 + c) * 768 + h * 64 + g * 8;
    const bf16x8 kf0 = *(const bf16x8*)(Kb + krow);
    const bf16x8 kf1 = *(const bf16x8*)(Kb + krow + 32);
    const int lv = (w * 512 + kt * 16 + g * 4 - shift) & 8191;
    s16x4 vf[4];
#pragma unroll
    for (int df = 0; df < 4; ++df)
      vf[df] = *(const s16x4*)(Vts + ((size_t)(df * 16 + c) << 13) + lv);

    const f32x4 z = {0.f, 0.f, 0.f, 0.f};
    s16x4 pk[4];
#pragma unroll
    for (int q = 0; q < 4; ++q) {
      f32x4 sc2 = __builtin_amdgcn_mfma_f32_16x16x32_bf16(kf0, qf[q][0], z, 0, 0, 0);
      sc2 = __builtin_amdgcn_mfma_f32_16x16x32_bf16(kf1, qf[q][1], sc2, 0, 0, 0);
      f32x4 pv;
      pv[0] = __builtin_amdgcn_exp2f(sc2[0] * CEXP);
      pv[1] = __builtin_amdgcn_exp2f(sc2[1] * CEXP);
      pv[2] = __builtin_amdgcn_exp2f(sc2[2] * CEXP);
      pv[3] = __builtin_amdgcn_exp2f(sc2[3] * CEXP);
      psum[q] += pv;
      pk[q][0] = (short)f2bf(pv[0]);
      pk[q][1] = (short)f2bf(pv[1]);
      pk[q][2] = (short)f2bf(pv[2]);
      pk[q][3] = (short)f2bf(pv[3]);
    }
#pragma unroll
    for (int df = 0; df < 4; ++df)
#pragma unroll
      for (int q = 0; q < 4; ++q)
        oacc[df][q] = __builtin_amdgcn_mfma_f32_16x16x16bf16_1k(vf[df], pk[q], oacc[df][q], 0, 0, 0);
  }

  const size_t orow0 = (size_t)(a * 32768 + qrow0);
#pragma unroll
  for (int q = 0; q < 4; ++q) {
    float ss = psum[q][0] + psum[q][1] + psum[q][2] + psum[q][3];
    ss += __shfl_xor(ss, 16);
    ss += __shfl_xor(ss, 32);
    const float inv = 1.f / ss;
#pragma unroll
    for (int df = 0; df < 4; ++df) {
      s16x4 po;
#pragma unroll
      for (int r = 0; r < 4; ++r) po[r] = (short)f2bf(oacc[df][q][r] * inv);
      *(s16x4*)(O + (orow0 + q * 16 + c) * 768 + h * 64 + df * 16 + g * 4) = po;
    }
  }
}

// ---------------------------------------------------------------------------
extern "C" void kernel_launch(void* const* d_in, const int* in_sizes, int n_in,
                              void* d_out, int out_size, void* d_ws, size_t ws_size,
                              hipStream_t stream) {
  const float* x       = (const float*)d_in[0];
  const float* ln1_g   = (const float*)d_in[1];
  const float* ln1_b   = (const float*)d_in[2];
  const float* ln2_g   = (const float*)d_in[3];
  const float* ln2_b   = (const float*)d_in[4];
  const float* a1_wqkv = (const float*)d_in[5];
  const float* a1_bqkv = (const float*)d_in[6];
  const float* a1_wo   = (const float*)d_in[7];
  const float* a1_bo   = (const float*)d_in[8];
  const float* a2_wqkv = (const float*)d_in[9];
  const float* a2_bqkv = (const float*)d_in[10];
  const float* a2_wo   = (const float*)d_in[11];
  const float* a2_bo   = (const float*)d_in[12];
  const float* fc_w    = (const float*)d_in[13];
  const float* fc_b    = (const float*)d_in[14];
  const float* proj_w  = (const float*)d_in[15];
  const float* proj_b  = (const float*)d_in[16];
  const int*   idxp    = (const int*)d_in[17];
  float* out = (float*)d_out;

  u16* p = (u16*)d_ws;
  u16* w1  = p; p += (size_t)2304 * 768;
  u16* w2  = p; p += (size_t)2304 * 768;
  u16* wo1 = p; p += (size_t)768 * 768;
  u16* wo2 = p; p += (size_t)768 * 768;
  u16* fcw = p; p += (size_t)3072 * 768;
  u16* pjw = p; p += (size_t)768 * 3072;
  u16* y   = p; p += (size_t)65536 * 768;
  u16* xv  = p; p += (size_t)65536 * 768;
  u16* Q1  = p; p += (size_t)32768 * 768;
  u16* K1  = p; p += (size_t)32768 * 768;
  u16* V1  = p; p += (size_t)32768 * 768;
  u16* Q2  = p; p += (size_t)32768 * 768;
  u16* K2  = p; p += (size_t)32768 * 768;
  u16* V2  = p; p += (size_t)32768 * 768;
  u16* Ob  = p; p += (size_t)65536 * 768;
  u16* hb  = Q1;  // MLP hidden aliases Q1..Ob

  cvtk<<<1728, 256, 0, stream>>>(a1_wqkv, w1, 2304 * 768);
  cvtk<<<1728, 256, 0, stream>>>(a2_wqkv, w2, 2304 * 768);
  cvtk<<<576,  256, 0, stream>>>(a1_wo, wo1, 768 * 768);
  cvtk<<<576,  256, 0, stream>>>(a2_wo, wo2, 768 * 768);
  cvtk<<<2304, 256, 0, stream>>>(fc_w, fcw, 3072 * 768);
  cvtk<<<2304, 256, 0, stream>>>(proj_w, pjw, 768 * 3072);

  lnk<<<16384, 256, 0, stream>>>(x, ln1_g, ln1_b, y, xv, 1);

  const size_t VS = (size_t)32768 * 768;
  gemm_bt<0><<<384, 512, 0, stream>>>(y,        w1,                  a1_bqkv,        Q1, 768, 768, nullptr, nullptr, 0);
  gemm_bt<0><<<384, 512, 0, stream>>>(y + VS,   w1 + 768 * 768,      a1_bqkv + 768,  K1, 768, 768, nullptr, nullptr, 0);
  gemm_bt<1><<<384, 512, 0, stream>>>(xv,       w1 + 2 * 768 * 768,  a1_bqkv + 1536, V1, 768, 768, nullptr, nullptr, 0);
  gemm_bt<0><<<384, 512, 0, stream>>>(y + VS,   w2,                  a2_bqkv,        Q2, 768, 768, nullptr, nullptr, 0);
  gemm_bt<0><<<384, 512, 0, stream>>>(y,        w2 + 768 * 768,      a2_bqkv + 768,  K2, 768, 768, nullptr, nullptr, 0);
  gemm_bt<1><<<384, 512, 0, stream>>>(xv + VS,  w2 + 2 * 768 * 768,  a2_bqkv + 1536, V2, 768, 768, nullptr, nullptr, 0);

  attnk<<<3072, 256, 0, stream>>>(Q1, K1, V1, Q2, K2, V2, Ob, idxp);

  gemm_bt<2><<<384, 512, 0, stream>>>(Ob,      wo1, a1_bo, out, 768, 768, x, idxp, 0);
  gemm_bt<2><<<384, 512, 0, stream>>>(Ob + VS, wo2, a2_bo, out, 768, 768, x, idxp, 1);

  lnk<<<16384, 256, 0, stream>>>(out, ln2_g, ln2_b, y, nullptr, 0);

  gemm_bt<3><<<3072, 512, 0, stream>>>(y, fcw, fc_b, hb, 3072, 768, nullptr, nullptr, 0);

  gemm_bt<4><<<768, 512, 0, stream>>>(hb, pjw, proj_b, out, 768, 3072, nullptr, nullptr, 0);
}